// Round 5
// baseline (509.510 us; speedup 1.0000x reference)
//
#include <hip/hip_runtime.h>

#define N_NODES 100000
#define N_EDGES 1600000
#define K_DIM   200
#define C_DIM   64
#define EPS_BN  1e-5f
#define NB_SCAN ((N_NODES + 255) / 256)   // 391
#define MT      128                       // gemm rows per block
#define NKB     25                        // 200 / 8 k-blocks
#define SLICE_ELEMS (N_NODES * 8)         // floats per channel-slice

// ===================== GEMM: register-tiled, writes slice-packed xwp =======
__global__ __launch_bounds__(256) void k_gemm2(const float* __restrict__ x,
                                               const float* __restrict__ W,
                                               float* __restrict__ xwp) {
    __shared__ float xT[8][MT];      // 4 KB, transposed x tile
    __shared__ float Wt[8][C_DIM];   // 2 KB
    int tid = threadIdx.x;
    int tx = tid & 15;               // col quad: channels tx*4..tx*4+3
    int ty = tid >> 4;               // row octet
    int row0 = blockIdx.x * MT;

    int lrow = tid >> 1;
    int lk   = (tid & 1) * 4;
    int grow = row0 + lrow;
    if (grow > N_NODES - 1) grow = N_NODES - 1;
    const float* xp = x + (size_t)grow * K_DIM + lk;
    int wk = tid >> 4;
    int wc = (tid & 15) * 4;

    float acc[8][4];
    #pragma unroll
    for (int i = 0; i < 8; ++i)
        #pragma unroll
        for (int j = 0; j < 4; ++j) acc[i][j] = 0.f;

    float4 xr = *(const float4*)xp;
    float4 wr = {0,0,0,0};
    if (tid < 128) wr = *(const float4*)(W + wk * C_DIM + wc);

    for (int kb = 0; kb < NKB; ++kb) {
        xT[lk + 0][lrow] = xr.x;
        xT[lk + 1][lrow] = xr.y;
        xT[lk + 2][lrow] = xr.z;
        xT[lk + 3][lrow] = xr.w;
        if (tid < 128) *(float4*)&Wt[wk][wc] = wr;
        __syncthreads();
        if (kb < NKB - 1) {
            xr = *(const float4*)(xp + (kb + 1) * 8);
            if (tid < 128) wr = *(const float4*)(W + ((kb + 1) * 8 + wk) * C_DIM + wc);
        }
        #pragma unroll
        for (int k = 0; k < 8; ++k) {
            float4 xa = *(const float4*)&xT[k][ty * 8];
            float4 xb = *(const float4*)&xT[k][ty * 8 + 4];
            float4 wv = *(const float4*)&Wt[k][tx * 4];
            float xv[8] = {xa.x, xa.y, xa.z, xa.w, xb.x, xb.y, xb.z, xb.w};
            #pragma unroll
            for (int i = 0; i < 8; ++i) {
                acc[i][0] = fmaf(xv[i], wv.x, acc[i][0]);
                acc[i][1] = fmaf(xv[i], wv.y, acc[i][1]);
                acc[i][2] = fmaf(xv[i], wv.z, acc[i][2]);
                acc[i][3] = fmaf(xv[i], wv.w, acc[i][3]);
            }
        }
        __syncthreads();
    }
    int sl  = tx >> 1;                 // slice 0..7
    int off = (tx & 1) * 4;            // 0 or 4 within slice row
    #pragma unroll
    for (int i = 0; i < 8; ++i) {
        int r = row0 + ty * 8 + i;
        if (r < N_NODES) {
            float4 o = {acc[i][0], acc[i][1], acc[i][2], acc[i][3]};
            *(float4*)(xwp + (size_t)sl * SLICE_ELEMS + (size_t)r * 8 + off) = o;
        }
    }
}

// ===================== CSR build ==========================================
__global__ void k_deg_int(const int* __restrict__ dst, int* __restrict__ deg) {
    int tid = blockIdx.x * blockDim.x + threadIdx.x;
    int stride = gridDim.x * blockDim.x;
    for (int e = tid; e < N_EDGES; e += stride)
        atomicAdd(&deg[dst[e]], 1);
}

__global__ void k_scan_block(const int* __restrict__ deg, int* __restrict__ bsum) {
    __shared__ int ls[256];
    int i = blockIdx.x * 256 + threadIdx.x;
    ls[threadIdx.x] = (i < N_NODES) ? deg[i] : 0;
    __syncthreads();
    for (int off = 128; off > 0; off >>= 1) {
        if (threadIdx.x < off) ls[threadIdx.x] += ls[threadIdx.x + off];
        __syncthreads();
    }
    if (threadIdx.x == 0) bsum[blockIdx.x] = ls[0];
}

__global__ void k_scan_top(const int* __restrict__ bsum, int* __restrict__ boff) {
    __shared__ int ls[512];
    int v = (threadIdx.x < NB_SCAN) ? bsum[threadIdx.x] : 0;
    ls[threadIdx.x] = v;
    __syncthreads();
    for (int off = 1; off < 512; off <<= 1) {
        int t = (threadIdx.x >= off) ? ls[threadIdx.x - off] : 0;
        __syncthreads();
        ls[threadIdx.x] += t;
        __syncthreads();
    }
    if (threadIdx.x < NB_SCAN) boff[threadIdx.x] = ls[threadIdx.x] - v; // exclusive
}

__global__ void k_scan_write(const int* __restrict__ deg, const int* __restrict__ boff,
                             int* __restrict__ row_start, float* __restrict__ dinv) {
    __shared__ int ls[256];
    int i = blockIdx.x * 256 + threadIdx.x;
    int v = (i < N_NODES) ? deg[i] : 0;
    ls[threadIdx.x] = v;
    __syncthreads();
    for (int off = 1; off < 256; off <<= 1) {        // inclusive scan
        int t = (threadIdx.x >= off) ? ls[threadIdx.x - off] : 0;
        __syncthreads();
        ls[threadIdx.x] += t;
        __syncthreads();
    }
    if (i < N_NODES) {
        row_start[i] = boff[blockIdx.x] + ls[threadIdx.x] - v;  // exclusive
        dinv[i] = rsqrtf((float)v + 1.0f);                      // +1 self loop
    }
    if (i == N_NODES - 1) row_start[N_NODES] = N_EDGES;
}

__global__ void k_fill(const int* __restrict__ src, const int* __restrict__ dst,
                       const int* __restrict__ row_start, int* __restrict__ cursor,
                       int* __restrict__ csr) {
    int tid = blockIdx.x * blockDim.x + threadIdx.x;
    int stride = gridDim.x * blockDim.x;
    for (int e = tid; e < N_EDGES; e += stride) {
        int d = dst[e];
        int pos = atomicAdd(&cursor[d], 1);
        csr[row_start[d] + pos] = src[e];
    }
}

// ===================== gather: channel-sliced, L2-resident per XCD =========
// slice = blockIdx % 8 -> XCD round-robin; slice working set = 3.2 MB < 4 MB L2.
// lane = (edge slot g = lane>>2, channel pair c2 = lane&3).
__global__ __launch_bounds__(256) void k_gath8(
        const int* __restrict__ csr, const int* __restrict__ row_start,
        const float* __restrict__ dinv, const float* __restrict__ xwp,
        const float* __restrict__ b, float* __restrict__ hp,
        float* __restrict__ stats) {
    int tid  = threadIdx.x;
    int lane = tid & 63;
    int g    = lane >> 2;       // edge slot 0..15
    int c2   = lane & 3;        // channel pair within slice
    int slice = blockIdx.x & 7;
    int wv  = (blockIdx.x >> 3) * 4 + (tid >> 6);     // wave id within slice
    int nwv = (gridDim.x >> 3) * 4;
    const float* xs = xwp + (size_t)slice * SLICE_ELEMS;
    float*       hs = hp  + (size_t)slice * SLICE_ELEMS;
    float2 bq = *(const float2*)(b + slice * 8 + 2 * c2);
    float2 s1 = {0, 0}, s2 = {0, 0};

    for (int n = wv; n < N_NODES; n += nwv) {
        int beg = row_start[n], end = row_start[n + 1];
        float2 acc = {0, 0};
        for (int j0 = beg; j0 < end; j0 += 32) {       // 2 chains in flight
            int j1 = j0 + g, j2 = j0 + 16 + g;
            if (j1 < end) {
                int   si = __builtin_nontemporal_load(csr + j1);
                float dv = dinv[si];
                float2 xv = *(const float2*)(xs + (size_t)si * 8 + 2 * c2);
                acc.x = fmaf(dv, xv.x, acc.x);
                acc.y = fmaf(dv, xv.y, acc.y);
            }
            if (j2 < end) {
                int   si = __builtin_nontemporal_load(csr + j2);
                float dv = dinv[si];
                float2 xv = *(const float2*)(xs + (size_t)si * 8 + 2 * c2);
                acc.x = fmaf(dv, xv.x, acc.x);
                acc.y = fmaf(dv, xv.y, acc.y);
            }
        }
        #pragma unroll
        for (int m = 4; m <= 32; m <<= 1) {            // reduce 16 slots
            acc.x += __shfl_xor(acc.x, m);
            acc.y += __shfl_xor(acc.y, m);
        }
        float dn = dinv[n];
        float2 xself = *(const float2*)(xs + (size_t)n * 8 + 2 * c2);
        float2 hv;
        hv.x = fmaxf(fmaf(dn, fmaf(dn, xself.x, acc.x), bq.x), 0.f);
        hv.y = fmaxf(fmaf(dn, fmaf(dn, xself.y, acc.y), bq.y), 0.f);
        if (g == 0) {
            *(float2*)(hs + (size_t)n * 8 + 2 * c2) = hv;
            s1.x += hv.x; s1.y += hv.y;
            s2.x = fmaf(hv.x, hv.x, s2.x);
            s2.y = fmaf(hv.y, hv.y, s2.y);
        }
    }

    __shared__ float sm[4][16];   // [wave][8 sums | 8 sumsqs]
    if (g == 0) {
        int wwb = tid >> 6;
        sm[wwb][2 * c2 + 0] = s1.x;
        sm[wwb][2 * c2 + 1] = s1.y;
        sm[wwb][8 + 2 * c2 + 0] = s2.x;
        sm[wwb][8 + 2 * c2 + 1] = s2.y;
    }
    __syncthreads();
    if (tid < 16) {
        float v = sm[0][tid] + sm[1][tid] + sm[2][tid] + sm[3][tid];
        int ch = slice * 8 + (tid & 7);
        unsafeAtomicAdd(&stats[(tid >> 3) * 64 + ch], v);
    }
}

// ---------------- BN scale/shift precompute (64 threads) -------------------
__global__ void k_scale(const float* __restrict__ stats_in, const float* __restrict__ bnw,
                        const float* __restrict__ bnb, float* __restrict__ scsh) {
    int c = threadIdx.x;   // 0..63
    float mean = stats_in[c] * (1.0f / N_NODES);
    float var  = stats_in[64 + c] * (1.0f / N_NODES) - mean * mean;
    float sc = rsqrtf(var + EPS_BN) * bnw[c];
    scsh[c]      = sc;                     // scale
    scsh[64 + c] = bnb[c] - mean * sc;     // shift
}

// ---------------- BN apply + un-permute: thread = node ---------------------
__global__ __launch_bounds__(256) void k_final_p(
        const float* __restrict__ hp, const float* __restrict__ scsh,
        float* __restrict__ out) {
    int n = blockIdx.x * blockDim.x + threadIdx.x;
    if (n >= N_NODES) return;
    #pragma unroll
    for (int s = 0; s < 8; ++s) {
        const float4* h4 = (const float4*)(hp + (size_t)s * SLICE_ELEMS + (size_t)n * 8);
        const float4* sc4 = (const float4*)(scsh + s * 8);
        const float4* sh4 = (const float4*)(scsh + 64 + s * 8);
        float4 a = h4[0], bb = h4[1];
        float4 sa = sc4[0], sb = sc4[1];
        float4 fa = sh4[0], fb = sh4[1];
        float4 o0, o1;
        o0.x = fmaf(a.x, sa.x, fa.x);  o0.y = fmaf(a.y, sa.y, fa.y);
        o0.z = fmaf(a.z, sa.z, fa.z);  o0.w = fmaf(a.w, sa.w, fa.w);
        o1.x = fmaf(bb.x, sb.x, fb.x); o1.y = fmaf(bb.y, sb.y, fb.y);
        o1.z = fmaf(bb.z, sb.z, fb.z); o1.w = fmaf(bb.w, sb.w, fb.w);
        float4* op = (float4*)(out + (size_t)n * C_DIM + s * 8);
        op[0] = o0; op[1] = o1;
    }
}

// ===========================================================================
extern "C" void kernel_launch(void* const* d_in, const int* in_sizes, int n_in,
                              void* d_out, int out_size, void* d_ws, size_t ws_size,
                              hipStream_t stream) {
    const float* x   = (const float*)d_in[0];
    const int*   ei  = (const int*)d_in[1];
    const float* W   = (const float*)d_in[2];
    const float* b   = (const float*)d_in[3];
    const float* bnw = (const float*)d_in[4];
    const float* bnb = (const float*)d_in[5];
    float* out = (float*)d_out;

    const int* src = ei;
    const int* dst = ei + N_EDGES;
    char* ws = (char*)d_ws;

    const size_t SZ_I = 400128;                 // 100000*4 padded
    const size_t OFF_CUR  = SZ_I;
    const size_t OFF_STAT = 2 * SZ_I;           // 1024 B: sums(256B) | scale/shift(512B)
    const size_t OFF_DINV = 2 * SZ_I + 1024;
    const size_t OFF_ROW  = 3 * SZ_I + 1024;
    const size_t OFF_BSUM = 4 * SZ_I + 1024;
    const size_t OFF_BOFF = 4 * SZ_I + 3072;
    const size_t OFF_CSR  = 4 * SZ_I + 5120;
    const size_t OFF_H    = OFF_CSR + (size_t)N_EDGES * 4;

    float* xwp = out;   // slice-packed xw lives in d_out until k_final_p overwrites
    const int GEMM_GRID = (N_NODES + MT - 1) / MT;   // 782

    int*   deg       = (int*)ws;
    int*   cursor    = (int*)(ws + OFF_CUR);
    float* stats     = (float*)(ws + OFF_STAT);
    float* scsh      = (float*)(ws + OFF_STAT + 256);
    float* dinv      = (float*)(ws + OFF_DINV);
    int*   row_start = (int*)(ws + OFF_ROW);
    int*   bsum      = (int*)(ws + OFF_BSUM);
    int*   boff      = (int*)(ws + OFF_BOFF);
    int*   csr       = (int*)(ws + OFF_CSR);
    float* hp        = (float*)(ws + OFF_H);

    hipMemsetAsync(d_ws, 0, OFF_STAT + 256, stream);  // deg, cursor, stat sums

    k_deg_int   <<<2048, 256, 0, stream>>>(dst, deg);
    k_scan_block<<<NB_SCAN, 256, 0, stream>>>(deg, bsum);
    k_scan_top  <<<1, 512, 0, stream>>>(bsum, boff);
    k_scan_write<<<NB_SCAN, 256, 0, stream>>>(deg, boff, row_start, dinv);
    k_fill      <<<2048, 256, 0, stream>>>(src, dst, row_start, cursor, csr);
    k_gemm2     <<<GEMM_GRID, 256, 0, stream>>>(x, W, xwp);
    k_gath8     <<<4096, 256, 0, stream>>>(csr, row_start, dinv, xwp, b, hp, stats);
    k_scale     <<<1, 64, 0, stream>>>(stats, bnw, bnb, scsh);
    k_final_p   <<<(N_NODES + 255) / 256, 256, 0, stream>>>(hp, scsh, out);
    (void)ws_size;
}

// Round 6
// 343.516 us; speedup vs baseline: 1.4832x; 1.4832x over previous
//
#include <hip/hip_runtime.h>

#define N_NODES 100000
#define N_EDGES 1600000
#define K_DIM   200
#define C_DIM   64
#define EPS_BN  1e-5f
#define NB_SCAN ((N_NODES + 255) / 256)   // 391
#define MT      128                       // gemm rows per block
#define NKB     25                        // 200 / 8 k-blocks
#define SLICE_U ((size_t)N_NODES * 16)    // ushorts per 16-ch bf16 slice

__device__ __forceinline__ ushort f2bf(float f) {
    unsigned u = __float_as_uint(f);
    u = (u + 0x7FFFu + ((u >> 16) & 1u)) >> 16;   // RNE
    return (ushort)u;
}

// ===================== GEMM: 128x64 tile -> pre-scaled bf16 4-slice xsp ====
__global__ __launch_bounds__(256) void k_gemm2(const float* __restrict__ x,
                                               const float* __restrict__ W,
                                               const float* __restrict__ dinv,
                                               ushort* __restrict__ xsp) {
    __shared__ float xT[8][MT];      // 4 KB
    __shared__ float Wt[8][C_DIM];   // 2 KB
    int tid = threadIdx.x;
    int tx = tid & 15;               // channels tx*4..tx*4+3
    int ty = tid >> 4;               // row octet
    int row0 = blockIdx.x * MT;

    int lrow = tid >> 1;
    int lk   = (tid & 1) * 4;
    int grow = row0 + lrow;
    if (grow > N_NODES - 1) grow = N_NODES - 1;
    const float* xp = x + (size_t)grow * K_DIM + lk;
    int wk = tid >> 4;
    int wc = (tid & 15) * 4;

    float acc[8][4];
    #pragma unroll
    for (int i = 0; i < 8; ++i)
        #pragma unroll
        for (int j = 0; j < 4; ++j) acc[i][j] = 0.f;

    float4 xr = *(const float4*)xp;
    float4 wr = {0,0,0,0};
    if (tid < 128) wr = *(const float4*)(W + wk * C_DIM + wc);

    for (int kb = 0; kb < NKB; ++kb) {
        xT[lk + 0][lrow] = xr.x;
        xT[lk + 1][lrow] = xr.y;
        xT[lk + 2][lrow] = xr.z;
        xT[lk + 3][lrow] = xr.w;
        if (tid < 128) *(float4*)&Wt[wk][wc] = wr;
        __syncthreads();
        if (kb < NKB - 1) {
            xr = *(const float4*)(xp + (kb + 1) * 8);
            if (tid < 128) wr = *(const float4*)(W + ((kb + 1) * 8 + wk) * C_DIM + wc);
        }
        #pragma unroll
        for (int k = 0; k < 8; ++k) {
            float4 xa = *(const float4*)&xT[k][ty * 8];
            float4 xb = *(const float4*)&xT[k][ty * 8 + 4];
            float4 wv = *(const float4*)&Wt[k][tx * 4];
            float xv[8] = {xa.x, xa.y, xa.z, xa.w, xb.x, xb.y, xb.z, xb.w};
            #pragma unroll
            for (int i = 0; i < 8; ++i) {
                acc[i][0] = fmaf(xv[i], wv.x, acc[i][0]);
                acc[i][1] = fmaf(xv[i], wv.y, acc[i][1]);
                acc[i][2] = fmaf(xv[i], wv.z, acc[i][2]);
                acc[i][3] = fmaf(xv[i], wv.w, acc[i][3]);
            }
        }
        __syncthreads();
    }
    int sl  = tx >> 2;                 // slice 0..3  (16 channels each)
    int pos = (tx & 3) * 4;            // ushort offset within slice row
    #pragma unroll
    for (int i = 0; i < 8; ++i) {
        int r = row0 + ty * 8 + i;
        if (r < N_NODES) {
            float dv = dinv[r];
            ushort4 o = {f2bf(acc[i][0] * dv), f2bf(acc[i][1] * dv),
                         f2bf(acc[i][2] * dv), f2bf(acc[i][3] * dv)};
            *(ushort4*)(xsp + (size_t)sl * SLICE_U + (size_t)r * 16 + pos) = o;
        }
    }
}

// ===================== CSR build ==========================================
__global__ void k_deg_int(const int* __restrict__ dst, int* __restrict__ deg) {
    int tid = blockIdx.x * blockDim.x + threadIdx.x;
    int stride = gridDim.x * blockDim.x;
    for (int e = tid; e < N_EDGES; e += stride)
        atomicAdd(&deg[dst[e]], 1);
}

__global__ void k_scan_block(const int* __restrict__ deg, int* __restrict__ bsum) {
    __shared__ int ls[256];
    int i = blockIdx.x * 256 + threadIdx.x;
    ls[threadIdx.x] = (i < N_NODES) ? deg[i] : 0;
    __syncthreads();
    for (int off = 128; off > 0; off >>= 1) {
        if (threadIdx.x < off) ls[threadIdx.x] += ls[threadIdx.x + off];
        __syncthreads();
    }
    if (threadIdx.x == 0) bsum[blockIdx.x] = ls[0];
}

__global__ void k_scan_top(const int* __restrict__ bsum, int* __restrict__ boff) {
    __shared__ int ls[512];
    int v = (threadIdx.x < NB_SCAN) ? bsum[threadIdx.x] : 0;
    ls[threadIdx.x] = v;
    __syncthreads();
    for (int off = 1; off < 512; off <<= 1) {
        int t = (threadIdx.x >= off) ? ls[threadIdx.x - off] : 0;
        __syncthreads();
        ls[threadIdx.x] += t;
        __syncthreads();
    }
    if (threadIdx.x < NB_SCAN) boff[threadIdx.x] = ls[threadIdx.x] - v; // exclusive
}

__global__ void k_scan_write(const int* __restrict__ deg, const int* __restrict__ boff,
                             int* __restrict__ row_start, float* __restrict__ dinv) {
    __shared__ int ls[256];
    int i = blockIdx.x * 256 + threadIdx.x;
    int v = (i < N_NODES) ? deg[i] : 0;
    ls[threadIdx.x] = v;
    __syncthreads();
    for (int off = 1; off < 256; off <<= 1) {        // inclusive scan
        int t = (threadIdx.x >= off) ? ls[threadIdx.x - off] : 0;
        __syncthreads();
        ls[threadIdx.x] += t;
        __syncthreads();
    }
    if (i < N_NODES) {
        row_start[i] = boff[blockIdx.x] + ls[threadIdx.x] - v;  // exclusive
        dinv[i] = rsqrtf((float)v + 1.0f);                      // +1 self loop
    }
    if (i == N_NODES - 1) row_start[N_NODES] = N_EDGES;
}

__global__ void k_fill(const int* __restrict__ src, const int* __restrict__ dst,
                       const int* __restrict__ row_start, int* __restrict__ cursor,
                       int* __restrict__ csr) {
    int tid = blockIdx.x * blockDim.x + threadIdx.x;
    int stride = gridDim.x * blockDim.x;
    for (int e = tid; e < N_EDGES; e += stride) {
        int d = dst[e];
        int pos = atomicAdd(&cursor[d], 1);
        csr[row_start[d] + pos] = src[e];
    }
}

// ===================== gather: lane = node, 16-ch bf16 slice, L2-resident ==
// slice = (blockIdx%8)>>1 -> one slice per XCD (2 XCDs share a slice).
#define UNPK0(u, k) { acc[k] = __uint_as_float((u) << 16); \
                      acc[k+1] = __uint_as_float((u) & 0xFFFF0000u); }
#define UNPKA(u, k) { acc[k] += __uint_as_float((u) << 16); \
                      acc[k+1] += __uint_as_float((u) & 0xFFFF0000u); }

__global__ __launch_bounds__(256) void k_gath4(
        const int* __restrict__ csr, const int* __restrict__ row_start,
        const float* __restrict__ dinv, const ushort* __restrict__ xsp,
        const float* __restrict__ b, float* __restrict__ hp2) {
    int tid  = threadIdx.x;
    int lane = tid & 63;
    int widx = tid >> 6;
    int bid  = blockIdx.x;
    int slice = (bid & 7) >> 1;
    int chunk = ((bid >> 3) * 2 + (bid & 1)) * 4 + widx;
    int nchunks = (gridDim.x >> 3) * 8;            // waves per slice
    const ushort* xs = xsp + (size_t)slice * SLICE_U;
    const float*  bs = b + slice * 16;

    for (int n0 = chunk * 64; n0 < N_NODES; n0 += nchunks * 64) {
        int n = n0 + lane;
        bool act = n < N_NODES;
        int beg = 0, end = 0;
        float dn = 0.f;
        float acc[16];
        if (act) {
            beg = row_start[n];
            end = row_start[n + 1];
            dn  = dinv[n];
            const uint4* rp = (const uint4*)(xs + (size_t)n * 16);  // self row
            uint4 a = rp[0], c = rp[1];
            UNPK0(a.x, 0)  UNPK0(a.y, 2)  UNPK0(a.z, 4)  UNPK0(a.w, 6)
            UNPK0(c.x, 8)  UNPK0(c.y, 10) UNPK0(c.z, 12) UNPK0(c.w, 14)
        } else {
            #pragma unroll
            for (int i = 0; i < 16; ++i) acc[i] = 0.f;
        }
        int j = beg;
        for (; j + 2 <= end; j += 2) {             // 2 rows in flight
            int s0 = csr[j], s1 = csr[j + 1];
            const uint4* p0 = (const uint4*)(xs + (size_t)s0 * 16);
            const uint4* p1 = (const uint4*)(xs + (size_t)s1 * 16);
            uint4 a0 = p0[0], c0 = p0[1];
            uint4 a1 = p1[0], c1 = p1[1];
            UNPKA(a0.x, 0)  UNPKA(a0.y, 2)  UNPKA(a0.z, 4)  UNPKA(a0.w, 6)
            UNPKA(c0.x, 8)  UNPKA(c0.y, 10) UNPKA(c0.z, 12) UNPKA(c0.w, 14)
            UNPKA(a1.x, 0)  UNPKA(a1.y, 2)  UNPKA(a1.z, 4)  UNPKA(a1.w, 6)
            UNPKA(c1.x, 8)  UNPKA(c1.y, 10) UNPKA(c1.z, 12) UNPKA(c1.w, 14)
        }
        if (j < end) {
            int s0 = csr[j];
            const uint4* p0 = (const uint4*)(xs + (size_t)s0 * 16);
            uint4 a0 = p0[0], c0 = p0[1];
            UNPKA(a0.x, 0)  UNPKA(a0.y, 2)  UNPKA(a0.z, 4)  UNPKA(a0.w, 6)
            UNPKA(c0.x, 8)  UNPKA(c0.y, 10) UNPKA(c0.z, 12) UNPKA(c0.w, 14)
        }
        if (act) {
            #pragma unroll
            for (int sub = 0; sub < 4; ++sub) {
                float4 hv;
                hv.x = fmaxf(fmaf(dn, acc[4*sub+0], bs[4*sub+0]), 0.f);
                hv.y = fmaxf(fmaf(dn, acc[4*sub+1], bs[4*sub+1]), 0.f);
                hv.z = fmaxf(fmaf(dn, acc[4*sub+2], bs[4*sub+2]), 0.f);
                hv.w = fmaxf(fmaf(dn, acc[4*sub+3], bs[4*sub+3]), 0.f);
                *(float4*)(hp2 + ((size_t)(slice * 4 + sub) * N_NODES + n) * 4) = hv;
            }
        }
    }
}

// ===================== BN stats over hp2 (region-major) ====================
__global__ __launch_bounds__(256) void k_stats(const float4* __restrict__ hp2,
                                               float* __restrict__ stats) {
    int tid = blockIdx.x * 256 + threadIdx.x;   // grid must be 512 blocks
    int q  = tid >> 13;                         // region 0..15 (channels q*4..q*4+3)
    int n0 = tid & 8191;
    float4 s1 = {0,0,0,0}, s2 = {0,0,0,0};
    for (int n = n0; n < N_NODES; n += 8192) {
        float4 v = hp2[(size_t)q * N_NODES + n];
        s1.x += v.x; s1.y += v.y; s1.z += v.z; s1.w += v.w;
        s2.x = fmaf(v.x, v.x, s2.x); s2.y = fmaf(v.y, v.y, s2.y);
        s2.z = fmaf(v.z, v.z, s2.z); s2.w = fmaf(v.w, v.w, s2.w);
    }
    __shared__ float4 l1[256], l2[256];
    l1[threadIdx.x] = s1; l2[threadIdx.x] = s2;
    __syncthreads();
    for (int off = 128; off > 0; off >>= 1) {
        if (threadIdx.x < off) {
            float4 a = l1[threadIdx.x + off], c = l2[threadIdx.x + off];
            l1[threadIdx.x].x += a.x; l1[threadIdx.x].y += a.y;
            l1[threadIdx.x].z += a.z; l1[threadIdx.x].w += a.w;
            l2[threadIdx.x].x += c.x; l2[threadIdx.x].y += c.y;
            l2[threadIdx.x].z += c.z; l2[threadIdx.x].w += c.w;
        }
        __syncthreads();
    }
    if (threadIdx.x == 0) {
        float4 a = l1[0], c = l2[0];
        unsafeAtomicAdd(&stats[q * 4 + 0], a.x);
        unsafeAtomicAdd(&stats[q * 4 + 1], a.y);
        unsafeAtomicAdd(&stats[q * 4 + 2], a.z);
        unsafeAtomicAdd(&stats[q * 4 + 3], a.w);
        unsafeAtomicAdd(&stats[64 + q * 4 + 0], c.x);
        unsafeAtomicAdd(&stats[64 + q * 4 + 1], c.y);
        unsafeAtomicAdd(&stats[64 + q * 4 + 2], c.z);
        unsafeAtomicAdd(&stats[64 + q * 4 + 3], c.w);
    }
}

// ---------------- BN scale/shift precompute (64 threads) -------------------
__global__ void k_scale(const float* __restrict__ stats_in, const float* __restrict__ bnw,
                        const float* __restrict__ bnb, float* __restrict__ scsh) {
    int c = threadIdx.x;   // 0..63
    float mean = stats_in[c] * (1.0f / N_NODES);
    float var  = stats_in[64 + c] * (1.0f / N_NODES) - mean * mean;
    float sc = rsqrtf(var + EPS_BN) * bnw[c];
    scsh[c]      = sc;
    scsh[64 + c] = bnb[c] - mean * sc;
}

// ---------------- BN apply + un-permute ------------------------------------
__global__ __launch_bounds__(256) void k_final_p(
        const float4* __restrict__ hp2, const float* __restrict__ scsh,
        float4* __restrict__ out4) {
    int tid = blockIdx.x * 256 + threadIdx.x;   // over N_NODES*16
    if (tid >= N_NODES * 16) return;
    int q = tid & 15;
    int n = tid >> 4;
    float4 v  = hp2[(size_t)q * N_NODES + n];
    float4 sc = *(const float4*)(scsh + q * 4);
    float4 sh = *(const float4*)(scsh + 64 + q * 4);
    float4 o;
    o.x = fmaf(v.x, sc.x, sh.x);
    o.y = fmaf(v.y, sc.y, sh.y);
    o.z = fmaf(v.z, sc.z, sh.z);
    o.w = fmaf(v.w, sc.w, sh.w);
    out4[tid] = o;                              // out[n][q*4..q*4+3]
}

// ===========================================================================
extern "C" void kernel_launch(void* const* d_in, const int* in_sizes, int n_in,
                              void* d_out, int out_size, void* d_ws, size_t ws_size,
                              hipStream_t stream) {
    const float* x   = (const float*)d_in[0];
    const int*   ei  = (const int*)d_in[1];
    const float* W   = (const float*)d_in[2];
    const float* b   = (const float*)d_in[3];
    const float* bnw = (const float*)d_in[4];
    const float* bnb = (const float*)d_in[5];
    float* out = (float*)d_out;

    const int* src = ei;
    const int* dst = ei + N_EDGES;
    char* ws = (char*)d_ws;

    const size_t SZ_I = 400128;                 // 100000*4 padded
    const size_t OFF_CUR  = SZ_I;
    const size_t OFF_STAT = 2 * SZ_I;           // 512B sums | 512B scale/shift
    const size_t OFF_DINV = 2 * SZ_I + 1024;
    const size_t OFF_ROW  = 3 * SZ_I + 1024;
    const size_t OFF_BSUM = 4 * SZ_I + 1024;
    const size_t OFF_BOFF = 4 * SZ_I + 3072;
    const size_t OFF_CSR  = 4 * SZ_I + 5120;
    const size_t OFF_H    = OFF_CSR + (size_t)N_EDGES * 4;

    ushort* xsp = (ushort*)out;   // 12.8 MB bf16 slice-packed, dead after k_gath4
    const int GEMM_GRID = (N_NODES + MT - 1) / MT;   // 782

    int*   deg       = (int*)ws;
    int*   cursor    = (int*)(ws + OFF_CUR);
    float* stats     = (float*)(ws + OFF_STAT);
    float* scsh      = (float*)(ws + OFF_STAT + 512);
    float* dinv      = (float*)(ws + OFF_DINV);
    int*   row_start = (int*)(ws + OFF_ROW);
    int*   bsum      = (int*)(ws + OFF_BSUM);
    int*   boff      = (int*)(ws + OFF_BOFF);
    int*   csr       = (int*)(ws + OFF_CSR);
    float* hp2       = (float*)(ws + OFF_H);

    hipMemsetAsync(d_ws, 0, OFF_STAT + 512, stream);  // deg, cursor, stat sums

    k_deg_int   <<<2048, 256, 0, stream>>>(dst, deg);
    k_scan_block<<<NB_SCAN, 256, 0, stream>>>(deg, bsum);
    k_scan_top  <<<1, 512, 0, stream>>>(bsum, boff);
    k_scan_write<<<NB_SCAN, 256, 0, stream>>>(deg, boff, row_start, dinv);
    k_fill      <<<2048, 256, 0, stream>>>(src, dst, row_start, cursor, csr);
    k_gemm2     <<<GEMM_GRID, 256, 0, stream>>>(x, W, dinv, xsp);
    k_gath4     <<<784, 256, 0, stream>>>(csr, row_start, dinv, xsp, b, hp2);
    k_stats     <<<512, 256, 0, stream>>>((const float4*)hp2, stats);
    k_scale     <<<1, 64, 0, stream>>>(stats, bnw, bnb, scsh);
    k_final_p   <<<(N_NODES * 16 + 255) / 256, 256, 0, stream>>>(
                    (const float4*)hp2, scsh, (float4*)out);
    (void)ws_size;
}

// Round 7
// 288.045 us; speedup vs baseline: 1.7689x; 1.1926x over previous
//
#include <hip/hip_runtime.h>

#define N_NODES 100000
#define N_EDGES 1600000
#define K_DIM   200
#define C_DIM   64
#define EPS_BN  1e-5f
#define NB_SCAN ((N_NODES + 255) / 256)   // 391
#define MT      128                       // gemm rows per block
#define NKB     25                        // 200 / 8 k-blocks
#define SLICE_U ((size_t)N_NODES * 16)    // ushorts per 16-ch bf16 slice
#define NPX     12500                     // nodes per XCD range

__device__ __forceinline__ ushort f2bf(float f) {
    unsigned u = __float_as_uint(f);
    u = (u + 0x7FFFu + ((u >> 16) & 1u)) >> 16;   // RNE
    return (ushort)u;
}

// ===================== GEMM: 128x64 tile -> pre-scaled bf16 4-slice xsp ====
__global__ __launch_bounds__(256) void k_gemm2(const float* __restrict__ x,
                                               const float* __restrict__ W,
                                               const float* __restrict__ dinv,
                                               ushort* __restrict__ xsp) {
    __shared__ float xT[8][MT];      // 4 KB
    __shared__ float Wt[8][C_DIM];   // 2 KB
    int tid = threadIdx.x;
    int tx = tid & 15;               // channels tx*4..tx*4+3
    int ty = tid >> 4;               // row octet
    int row0 = blockIdx.x * MT;

    int lrow = tid >> 1;
    int lk   = (tid & 1) * 4;
    int grow = row0 + lrow;
    if (grow > N_NODES - 1) grow = N_NODES - 1;
    const float* xp = x + (size_t)grow * K_DIM + lk;
    int wk = tid >> 4;
    int wc = (tid & 15) * 4;

    float acc[8][4];
    #pragma unroll
    for (int i = 0; i < 8; ++i)
        #pragma unroll
        for (int j = 0; j < 4; ++j) acc[i][j] = 0.f;

    float4 xr = *(const float4*)xp;
    float4 wr = {0,0,0,0};
    if (tid < 128) wr = *(const float4*)(W + wk * C_DIM + wc);

    for (int kb = 0; kb < NKB; ++kb) {
        xT[lk + 0][lrow] = xr.x;
        xT[lk + 1][lrow] = xr.y;
        xT[lk + 2][lrow] = xr.z;
        xT[lk + 3][lrow] = xr.w;
        if (tid < 128) *(float4*)&Wt[wk][wc] = wr;
        __syncthreads();
        if (kb < NKB - 1) {
            xr = *(const float4*)(xp + (kb + 1) * 8);
            if (tid < 128) wr = *(const float4*)(W + ((kb + 1) * 8 + wk) * C_DIM + wc);
        }
        #pragma unroll
        for (int k = 0; k < 8; ++k) {
            float4 xa = *(const float4*)&xT[k][ty * 8];
            float4 xb = *(const float4*)&xT[k][ty * 8 + 4];
            float4 wv = *(const float4*)&Wt[k][tx * 4];
            float xv[8] = {xa.x, xa.y, xa.z, xa.w, xb.x, xb.y, xb.z, xb.w};
            #pragma unroll
            for (int i = 0; i < 8; ++i) {
                acc[i][0] = fmaf(xv[i], wv.x, acc[i][0]);
                acc[i][1] = fmaf(xv[i], wv.y, acc[i][1]);
                acc[i][2] = fmaf(xv[i], wv.z, acc[i][2]);
                acc[i][3] = fmaf(xv[i], wv.w, acc[i][3]);
            }
        }
        __syncthreads();
    }
    int sl  = tx >> 2;                 // slice 0..3  (16 channels each)
    int pos = (tx & 3) * 4;            // ushort offset within slice row
    #pragma unroll
    for (int i = 0; i < 8; ++i) {
        int r = row0 + ty * 8 + i;
        if (r < N_NODES) {
            float dv = dinv[r];
            ushort4 o = {f2bf(acc[i][0] * dv), f2bf(acc[i][1] * dv),
                         f2bf(acc[i][2] * dv), f2bf(acc[i][3] * dv)};
            *(ushort4*)(xsp + (size_t)sl * SLICE_U + (size_t)r * 16 + pos) = o;
        }
    }
}

// ===================== CSR build ==========================================
__global__ void k_deg4(const int4* __restrict__ dst4, int* __restrict__ deg) {
    int tid = blockIdx.x * blockDim.x + threadIdx.x;
    int stride = gridDim.x * blockDim.x;
    for (int i = tid; i < N_EDGES / 4; i += stride) {
        int4 d = dst4[i];
        atomicAdd(&deg[d.x], 1);
        atomicAdd(&deg[d.y], 1);
        atomicAdd(&deg[d.z], 1);
        atomicAdd(&deg[d.w], 1);
    }
}

__global__ void k_scan_block(const int* __restrict__ deg, int* __restrict__ bsum) {
    __shared__ int ls[256];
    int i = blockIdx.x * 256 + threadIdx.x;
    ls[threadIdx.x] = (i < N_NODES) ? deg[i] : 0;
    __syncthreads();
    for (int off = 128; off > 0; off >>= 1) {
        if (threadIdx.x < off) ls[threadIdx.x] += ls[threadIdx.x + off];
        __syncthreads();
    }
    if (threadIdx.x == 0) bsum[blockIdx.x] = ls[0];
}

__global__ void k_scan_top(const int* __restrict__ bsum, int* __restrict__ boff) {
    __shared__ int ls[512];
    int v = (threadIdx.x < NB_SCAN) ? bsum[threadIdx.x] : 0;
    ls[threadIdx.x] = v;
    __syncthreads();
    for (int off = 1; off < 512; off <<= 1) {
        int t = (threadIdx.x >= off) ? ls[threadIdx.x - off] : 0;
        __syncthreads();
        ls[threadIdx.x] += t;
        __syncthreads();
    }
    if (threadIdx.x < NB_SCAN) boff[threadIdx.x] = ls[threadIdx.x] - v; // exclusive
}

__global__ void k_scan_write(const int* __restrict__ deg, const int* __restrict__ boff,
                             int* __restrict__ row_start, float* __restrict__ dinv) {
    __shared__ int ls[256];
    int i = blockIdx.x * 256 + threadIdx.x;
    int v = (i < N_NODES) ? deg[i] : 0;
    ls[threadIdx.x] = v;
    __syncthreads();
    for (int off = 1; off < 256; off <<= 1) {        // inclusive scan
        int t = (threadIdx.x >= off) ? ls[threadIdx.x - off] : 0;
        __syncthreads();
        ls[threadIdx.x] += t;
        __syncthreads();
    }
    if (i < N_NODES) {
        row_start[i] = boff[blockIdx.x] + ls[threadIdx.x] - v;  // exclusive
        dinv[i] = rsqrtf((float)v + 1.0f);                      // +1 self loop
    }
    if (i == N_NODES - 1) row_start[N_NODES] = N_EDGES;
}

// XCD-range-partitioned fill: block bid&7 handles dst in [lo, lo+NPX).
// csr region per range (~800 KB) is written only by one XCD -> lines fill
// completely in its L2, write back once (~6.4 MB total vs 102 MB).
__global__ __launch_bounds__(256) void k_fill8(
        const int4* __restrict__ src4, const int4* __restrict__ dst4,
        const int* __restrict__ row_start, int* __restrict__ cursor,
        int* __restrict__ csr) {
    unsigned lo = (blockIdx.x & 7) * NPX;
    int i0 = (blockIdx.x >> 3) * 256 + threadIdx.x;
    int stride = (gridDim.x >> 3) * 256;
    for (int i = i0; i < N_EDGES / 4; i += stride) {
        int4 d = dst4[i];
        int4 s = src4[i];
        if ((unsigned)(d.x - lo) < NPX) { int p = atomicAdd(&cursor[d.x], 1); csr[row_start[d.x] + p] = s.x; }
        if ((unsigned)(d.y - lo) < NPX) { int p = atomicAdd(&cursor[d.y], 1); csr[row_start[d.y] + p] = s.y; }
        if ((unsigned)(d.z - lo) < NPX) { int p = atomicAdd(&cursor[d.z], 1); csr[row_start[d.z] + p] = s.z; }
        if ((unsigned)(d.w - lo) < NPX) { int p = atomicAdd(&cursor[d.w], 1); csr[row_start[d.w] + p] = s.w; }
    }
}

// ===================== gather: lane = node, bf16 slice, fused BN stats =====
#define UNPK0(u, k) { acc[k] = __uint_as_float((u) << 16); \
                      acc[k+1] = __uint_as_float((u) & 0xFFFF0000u); }
#define UNPKA(u, k) { acc[k] += __uint_as_float((u) << 16); \
                      acc[k+1] += __uint_as_float((u) & 0xFFFF0000u); }

__global__ __launch_bounds__(256) void k_gath4(
        const int* __restrict__ csr, const int* __restrict__ row_start,
        const float* __restrict__ dinv, const ushort* __restrict__ xsp,
        const float* __restrict__ b, float* __restrict__ hp2,
        float* __restrict__ stats) {
    int tid  = threadIdx.x;
    int lane = tid & 63;
    int widx = tid >> 6;
    int bid  = blockIdx.x;
    int slice = (bid & 7) >> 1;
    int chunk = ((bid >> 3) * 2 + (bid & 1)) * 4 + widx;
    int nchunks = (gridDim.x >> 3) * 8;            // waves per slice
    const ushort* xs = xsp + (size_t)slice * SLICE_U;
    const float*  bs = b + slice * 16;
    float s1[16], s2[16];
    #pragma unroll
    for (int i = 0; i < 16; ++i) { s1[i] = 0.f; s2[i] = 0.f; }

    for (int n0 = chunk * 64; n0 < N_NODES; n0 += nchunks * 64) {
        int n = n0 + lane;
        bool act = n < N_NODES;
        int beg = 0, end = 0;
        float dn = 0.f;
        float acc[16];
        if (act) {
            beg = row_start[n];
            end = row_start[n + 1];
            dn  = dinv[n];
            const uint4* rp = (const uint4*)(xs + (size_t)n * 16);  // self row
            uint4 a = rp[0], c = rp[1];
            UNPK0(a.x, 0)  UNPK0(a.y, 2)  UNPK0(a.z, 4)  UNPK0(a.w, 6)
            UNPK0(c.x, 8)  UNPK0(c.y, 10) UNPK0(c.z, 12) UNPK0(c.w, 14)
        } else {
            #pragma unroll
            for (int i = 0; i < 16; ++i) acc[i] = 0.f;
        }
        int j = beg;
        for (; j + 2 <= end; j += 2) {             // 2 rows in flight
            int s0 = csr[j], s1e = csr[j + 1];
            const uint4* p0 = (const uint4*)(xs + (size_t)s0 * 16);
            const uint4* p1 = (const uint4*)(xs + (size_t)s1e * 16);
            uint4 a0 = p0[0], c0 = p0[1];
            uint4 a1 = p1[0], c1 = p1[1];
            UNPKA(a0.x, 0)  UNPKA(a0.y, 2)  UNPKA(a0.z, 4)  UNPKA(a0.w, 6)
            UNPKA(c0.x, 8)  UNPKA(c0.y, 10) UNPKA(c0.z, 12) UNPKA(c0.w, 14)
            UNPKA(a1.x, 0)  UNPKA(a1.y, 2)  UNPKA(a1.z, 4)  UNPKA(a1.w, 6)
            UNPKA(c1.x, 8)  UNPKA(c1.y, 10) UNPKA(c1.z, 12) UNPKA(c1.w, 14)
        }
        if (j < end) {
            int s0 = csr[j];
            const uint4* p0 = (const uint4*)(xs + (size_t)s0 * 16);
            uint4 a0 = p0[0], c0 = p0[1];
            UNPKA(a0.x, 0)  UNPKA(a0.y, 2)  UNPKA(a0.z, 4)  UNPKA(a0.w, 6)
            UNPKA(c0.x, 8)  UNPKA(c0.y, 10) UNPKA(c0.z, 12) UNPKA(c0.w, 14)
        }
        if (act) {
            #pragma unroll
            for (int sub = 0; sub < 4; ++sub) {
                float4 hv;
                hv.x = fmaxf(fmaf(dn, acc[4*sub+0], bs[4*sub+0]), 0.f);
                hv.y = fmaxf(fmaf(dn, acc[4*sub+1], bs[4*sub+1]), 0.f);
                hv.z = fmaxf(fmaf(dn, acc[4*sub+2], bs[4*sub+2]), 0.f);
                hv.w = fmaxf(fmaf(dn, acc[4*sub+3], bs[4*sub+3]), 0.f);
                *(float4*)(hp2 + ((size_t)(slice * 4 + sub) * N_NODES + n) * 4) = hv;
                s1[4*sub+0] += hv.x; s2[4*sub+0] = fmaf(hv.x, hv.x, s2[4*sub+0]);
                s1[4*sub+1] += hv.y; s2[4*sub+1] = fmaf(hv.y, hv.y, s2[4*sub+1]);
                s1[4*sub+2] += hv.z; s2[4*sub+2] = fmaf(hv.z, hv.z, s2[4*sub+2]);
                s1[4*sub+3] += hv.w; s2[4*sub+3] = fmaf(hv.w, hv.w, s2[4*sub+3]);
            }
        }
    }

    // wave reduce 32 values, then block reduce via LDS, then atomics
    __shared__ float red[4][32];
    #pragma unroll
    for (int i = 0; i < 16; ++i) {
        float a = s1[i], c = s2[i];
        #pragma unroll
        for (int m = 1; m <= 32; m <<= 1) {
            a += __shfl_xor(a, m);
            c += __shfl_xor(c, m);
        }
        if (lane == 0) { red[widx][i] = a; red[widx][16 + i] = c; }
    }
    __syncthreads();
    if (tid < 32) {
        float v = red[0][tid] + red[1][tid] + red[2][tid] + red[3][tid];
        int ch = slice * 16 + (tid & 15);
        unsafeAtomicAdd(&stats[(tid >> 4) * 64 + ch], v);
    }
}

// ---------------- BN scale/shift precompute (64 threads) -------------------
__global__ void k_scale(const float* __restrict__ stats_in, const float* __restrict__ bnw,
                        const float* __restrict__ bnb, float* __restrict__ scsh) {
    int c = threadIdx.x;   // 0..63
    float mean = stats_in[c] * (1.0f / N_NODES);
    float var  = stats_in[64 + c] * (1.0f / N_NODES) - mean * mean;
    float sc = rsqrtf(var + EPS_BN) * bnw[c];
    scsh[c]      = sc;
    scsh[64 + c] = bnb[c] - mean * sc;
}

// ---------------- BN apply + un-permute ------------------------------------
__global__ __launch_bounds__(256) void k_final_p(
        const float4* __restrict__ hp2, const float* __restrict__ scsh,
        float4* __restrict__ out4) {
    int tid = blockIdx.x * 256 + threadIdx.x;   // over N_NODES*16
    if (tid >= N_NODES * 16) return;
    int q = tid & 15;
    int n = tid >> 4;
    float4 v  = hp2[(size_t)q * N_NODES + n];
    float4 sc = *(const float4*)(scsh + q * 4);
    float4 sh = *(const float4*)(scsh + 64 + q * 4);
    float4 o;
    o.x = fmaf(v.x, sc.x, sh.x);
    o.y = fmaf(v.y, sc.y, sh.y);
    o.z = fmaf(v.z, sc.z, sh.z);
    o.w = fmaf(v.w, sc.w, sh.w);
    out4[tid] = o;                              // out[n][q*4..q*4+3]
}

// ===========================================================================
extern "C" void kernel_launch(void* const* d_in, const int* in_sizes, int n_in,
                              void* d_out, int out_size, void* d_ws, size_t ws_size,
                              hipStream_t stream) {
    const float* x   = (const float*)d_in[0];
    const int*   ei  = (const int*)d_in[1];
    const float* W   = (const float*)d_in[2];
    const float* b   = (const float*)d_in[3];
    const float* bnw = (const float*)d_in[4];
    const float* bnb = (const float*)d_in[5];
    float* out = (float*)d_out;

    const int* src = ei;
    const int* dst = ei + N_EDGES;
    char* ws = (char*)d_ws;

    const size_t SZ_I = 400128;                 // 100000*4 padded
    const size_t OFF_CUR  = SZ_I;
    const size_t OFF_STAT = 2 * SZ_I;           // 512B sums | 512B scale/shift
    const size_t OFF_DINV = 2 * SZ_I + 1024;
    const size_t OFF_ROW  = 3 * SZ_I + 1024;
    const size_t OFF_BSUM = 4 * SZ_I + 1024;
    const size_t OFF_BOFF = 4 * SZ_I + 3072;
    const size_t OFF_CSR  = 4 * SZ_I + 5120;
    const size_t OFF_H    = OFF_CSR + (size_t)N_EDGES * 4;

    ushort* xsp = (ushort*)out;   // 12.8 MB bf16 slice-packed, dead after k_gath4
    const int GEMM_GRID = (N_NODES + MT - 1) / MT;   // 782

    int*   deg       = (int*)ws;
    int*   cursor    = (int*)(ws + OFF_CUR);
    float* stats     = (float*)(ws + OFF_STAT);
    float* scsh      = (float*)(ws + OFF_STAT + 512);
    float* dinv      = (float*)(ws + OFF_DINV);
    int*   row_start = (int*)(ws + OFF_ROW);
    int*   bsum      = (int*)(ws + OFF_BSUM);
    int*   boff      = (int*)(ws + OFF_BOFF);
    int*   csr       = (int*)(ws + OFF_CSR);
    float* hp2       = (float*)(ws + OFF_H);

    hipMemsetAsync(d_ws, 0, OFF_STAT + 512, stream);  // deg, cursor, stat sums

    k_deg4      <<<1024, 256, 0, stream>>>((const int4*)dst, deg);
    k_scan_block<<<NB_SCAN, 256, 0, stream>>>(deg, bsum);
    k_scan_top  <<<1, 512, 0, stream>>>(bsum, boff);
    k_scan_write<<<NB_SCAN, 256, 0, stream>>>(deg, boff, row_start, dinv);
    k_fill8     <<<2048, 256, 0, stream>>>((const int4*)src, (const int4*)dst,
                                           row_start, cursor, csr);
    k_gemm2     <<<GEMM_GRID, 256, 0, stream>>>(x, W, dinv, xsp);
    k_gath4     <<<1568, 256, 0, stream>>>(csr, row_start, dinv, xsp, b, hp2, stats);
    k_scale     <<<1, 64, 0, stream>>>(stats, bnw, bnb, scsh);
    k_final_p   <<<(N_NODES * 16 + 255) / 256, 256, 0, stream>>>(
                    (const float4*)hp2, scsh, (float4*)out);
    (void)ws_size;
}